// Round 14
// baseline (2437.047 us; speedup 1.0000x reference)
//
#include <hip/hip_runtime.h>
#include <hip/hip_bf16.h>

// TensorizedRNN: m1/m2 = einsum('bj,bk,ljk->bl', h, x, W{1,2}) as bf16-MFMA GEMM
// with virtual A = h (outer) x, K = 1024*262144.
// B=1024, I2=256, H=512, N=1024 (W1||W2), J=1024.
//
// R14 = R9 (best: bilin 865us / total 797us) + WAVE-STAGGERED js ORDER.
// R13 post-mortem: 2-blocks/CU spilled (644MB) + W double-fetch; reverted.
// R9 accounting: stage wall 16.2k cyc/SIMD vs pipe SUM ~13k (MFMA 5.0k +
// VALU 3.3k + LDS 2.2k + mem 2.5k) -> ZERO inter-pipe overlap = lockstep
// convoy (4 waves/SIMD hit the same pipe simultaneously at every phase).
// Fix: odd waves run js 7->0, even waves 0->7 (static unroll both orders,
// wave-uniform branch, zero register delta) -> wave pairs sit in different
// phases -> matrix/VALU/LDS pipes interleave. setprio now has role-split
// to arbitrate (T5 prerequisite).
// Spill detector: WRITE_SIZE must stay ~72 MB.

typedef __attribute__((ext_vector_type(8))) short short8;
typedef __attribute__((ext_vector_type(4))) float f32x4;
typedef __attribute__((ext_vector_type(2))) float f32x2;
typedef unsigned short ushort_t;

// f32 pair -> packed bf16 (low16 = a, high16 = b), single HW instr
__device__ __forceinline__ unsigned cvtpk(float a, float b) {
  unsigned r;
  asm("v_cvt_pk_bf16_f32 %0, %1, %2" : "=v"(r) : "v"(a), "v"(b));
  return r;
}

// packed f32 multiply, single HW instr
__device__ __forceinline__ f32x2 pkmul(f32x2 a, f32x2 b) {
  f32x2 r;
  asm("v_pk_mul_f32 %0, %1, %2" : "=v"(r) : "v"(a), "v"(b));
  return r;
}

__device__ __forceinline__ ushort_t f2bu(float f) {
  __hip_bfloat16 b = __float2bfloat16(f);
  union { __hip_bfloat16 b; ushort_t u; } cv;
  cv.b = b;
  return cv.u;
}

// ---------------- prep: hb16[b][j], xb16[b][kx], WmergeT[l][j] (all bf16) ---
__global__ void prep_k(const float* __restrict__ in0, const float* __restrict__ in1,
                       const float* __restrict__ s0, const float* __restrict__ s1,
                       const float* __restrict__ Wm,
                       ushort_t* __restrict__ hb, ushort_t* __restrict__ xb,
                       ushort_t* __restrict__ WmT) {
  __shared__ float tl[64][65];
  const int bid = blockIdx.x, t = threadIdx.x;
  if (bid < 256) {  // hb16: 1M elems, 4096/block
#pragma unroll
    for (int i = 0; i < 4; ++i) {
      int e = bid * 4096 + i * 1024 + t * 4;
      int b = e >> 10, j = e & 1023;
      const float* src = (j < 512) ? (s0 + (size_t)b * 512 + j)
                                   : (s1 + (size_t)b * 512 + j - 512);
      float4 v = *(const float4*)src;
      ushort4 o;
      o.x = f2bu(v.x); o.y = f2bu(v.y); o.z = f2bu(v.z); o.w = f2bu(v.w);
      *(ushort4*)(hb + e) = o;
    }
  } else if (bid < 272) {  // xb16: 256K elems, 16384/block
#pragma unroll
    for (int i = 0; i < 16; ++i) {
      int e = (bid - 256) * 16384 + i * 1024 + t * 4;
      int b = e >> 8, kx = e & 255;
      const float* src = (kx < 128) ? (in0 + (size_t)b * 128 + kx)
                                    : (in1 + (size_t)b * 128 + kx - 128);
      float4 v = *(const float4*)src;
      ushort4 o;
      o.x = f2bu(v.x); o.y = f2bu(v.y); o.z = f2bu(v.z); o.w = f2bu(v.w);
      *(ushort4*)(xb + e) = o;
    }
  } else {  // Wmerge [1024][512] -> WmT [512][1024], 64x64 tiles
    int q = bid - 272;           // 0..127
    int j0 = (q >> 3) * 64;
    int l0 = (q & 7) * 64;
#pragma unroll
    for (int i = 0; i < 16; ++i) {
      int idx = i * 256 + t; int r = idx >> 6, c = idx & 63;
      tl[r][c] = Wm[(size_t)(j0 + r) * 512 + l0 + c];
    }
    __syncthreads();
#pragma unroll
    for (int i = 0; i < 16; ++i) {
      int idx = i * 256 + t; int r = idx >> 6, c = idx & 63;
      WmT[(size_t)(l0 + r) * 1024 + j0 + c] = f2bu(tl[c][r]);
    }
  }
}

// one js iteration: optional prefetch of next js's B frags, A-gen, 8 MFMA.
#define JS_ITER(JS, JSN, HASNEXT)                                              \
  {                                                                            \
    const int pb_ = (JS) & 1, nb_ = pb_ ^ 1;                                   \
    if (HASNEXT) {                                                             \
      _Pragma("unroll")                                                        \
      for (int nc = 0; nc < 2; ++nc) {                                         \
        int col = nc * 16 + l15;                                               \
        int byte = col * 512 + (((JSN) * 64 + lg * 16) ^ ((col & 7) << 4));    \
        bfr[nb_][nc] = *(const short8*)(rb + byte);                            \
      }                                                                        \
    }                                                                          \
    __builtin_amdgcn_s_setprio(1);                                             \
    _Pragma("unroll")                                                          \
    for (int g = 0; g < 4; ++g) {                                              \
      unsigned hwrd = ((JS) < 2) ? hc[g].x : ((JS) < 4) ? hc[g].y              \
                     : ((JS) < 6) ? hc[g].z : hc[g].w;                         \
      float hf = __uint_as_float(((JS) & 1) ? (hwrd & 0xFFFF0000u)             \
                                            : (hwrd << 16));                   \
      f32x2 hf2; hf2[0] = hf; hf2[1] = hf;                                     \
      union { unsigned u[4]; short8 s; } av;                                   \
      _Pragma("unroll")                                                        \
      for (int p = 0; p < 4; ++p) {                                            \
        f32x2 m = pkmul(xf[g][p], hf2);                                        \
        av.u[p] = cvtpk(m[0], m[1]);                                           \
      }                                                                        \
      short8 afr = av.s;                                                       \
      _Pragma("unroll")                                                        \
      for (int nc = 0; nc < 2; ++nc)                                           \
        acc[g][nc] = __builtin_amdgcn_mfma_f32_16x16x32_bf16(                  \
            afr, bfr[pb_][nc], acc[g][nc], 0, 0, 0);                           \
    }                                                                          \
    __builtin_amdgcn_s_setprio(0);                                             \
  }

// ---------------- main bilinear GEMM --------------------------------------
// grid (32 ntiles, 16 kchunks) = 512 blocks, 1024 threads (16 waves).
// Block: all 1024 batch rows x 32 n-cols; K-chunk = 512 j's x 32 kx's,
// consumed in 64 stages of 8 j. Even waves js 0->7, odd waves js 7->0.
__global__ __launch_bounds__(1024)
__attribute__((amdgpu_waves_per_eu(4, 4))) void bilin_k(
    const float* __restrict__ W1, const float* __restrict__ W2,
    const ushort_t* __restrict__ hb, const ushort_t* __restrict__ xb,
    float* __restrict__ accg) {
  // 2 x 16 KB bf16 tile + pad to 84 KB so only ONE block fits per CU.
  __shared__ uint4 smemv[5376];  // 86016 B

  const int ntile = blockIdx.x;         // 0..31 -> n cols ntile*32..+31
  const int chunk = blockIdx.y;         // 0..15
  const int kxwin = (chunk & 7) * 32;   // kx window
  const int jbase0 = (chunk >> 3) * 512;
  const int tid = threadIdx.x;
  const int wave = tid >> 6;
  const int lane = tid & 63;
  const int l15 = lane & 15;
  const int lg = lane >> 4;
  const int wrow = wave * 64;           // wave's 64 batch rows

  // W-staging role: col 0..31, j-sub 0..7, 8-float chunk 0..3
  const int scol = tid >> 5;
  const int sj = (tid & 31) >> 2;
  const int sc4 = tid & 3;
  const int wbyte = scol * 512 + ((sj * 64 + sc4 * 16) ^ ((scol & 7) << 4));

  const float* Wsel = (ntile < 16) ? W1 : W2;
  const float* gW = Wsel + (size_t)(ntile & 15) * 32 * 262144 +
                    (size_t)scol * 262144 + (size_t)(jbase0 + sj) * 256 +
                    kxwin + sc4 * 8;

  // per-lane x cache, unpacked to f32 pairs (t-invariant): 32 regs
  f32x2 xf[4][4];
#pragma unroll
  for (int g = 0; g < 4; ++g) {
    uint4 xw = *(const uint4*)(xb + (size_t)(wrow + g * 16 + l15) * 256 + kxwin + lg * 8);
    unsigned w[4] = {xw.x, xw.y, xw.z, xw.w};
#pragma unroll
    for (int p = 0; p < 4; ++p) {
      xf[g][p][0] = __uint_as_float(w[p] << 16);
      xf[g][p][1] = __uint_as_float(w[p] & 0xFFFF0000u);
    }
  }

  f32x4 acc[4][2];
  const f32x4 z4 = {0.f, 0.f, 0.f, 0.f};
#pragma unroll
  for (int g = 0; g < 4; ++g)
#pragma unroll
    for (int nc = 0; nc < 2; ++nc) acc[g][nc] = z4;

  // prologue: stage t=0 into B16[0]
  {
    float4 wa = *(const float4*)gW;
    float4 wb = *(const float4*)(gW + 4);
    uint4 pk;
    pk.x = cvtpk(wa.x, wa.y); pk.y = cvtpk(wa.z, wa.w);
    pk.z = cvtpk(wb.x, wb.y); pk.w = cvtpk(wb.z, wb.w);
    *(uint4*)((char*)smemv + wbyte) = pk;
  }
  __syncthreads();

  int cur = 0;
  for (int t = 0; t < 64; ++t) {
    const int nxt = cur ^ 1;
    // issue next-stage W loads early; consumed after compute (latency hidden)
    float4 wa, wb;
    if (t < 63) {
      const float* gp = gW + (size_t)(t + 1) * 2048;
      wa = *(const float4*)gp;
      wb = *(const float4*)(gp + 4);
    }

    // h for this stage: 8 j's per row (16 B), 4 row-groups
    const int jw = jbase0 + t * 8;
    uint4 hc[4];
#pragma unroll
    for (int g = 0; g < 4; ++g)
      hc[g] = *(const uint4*)(hb + (size_t)(wrow + g * 16 + l15) * 1024 + jw);

    const char* rb = (const char*)smemv + cur * 16384;
    short8 bfr[2][2];

    if ((wave & 1) == 0) {
      // even waves: js 0 -> 7
#pragma unroll
      for (int nc = 0; nc < 2; ++nc) {
        int col = nc * 16 + l15;
        int byte = col * 512 + ((lg * 16) ^ ((col & 7) << 4));
        bfr[0][nc] = *(const short8*)(rb + byte);
      }
      JS_ITER(0, 1, 1) JS_ITER(1, 2, 1) JS_ITER(2, 3, 1) JS_ITER(3, 4, 1)
      JS_ITER(4, 5, 1) JS_ITER(5, 6, 1) JS_ITER(6, 7, 1) JS_ITER(7, 0, 0)
    } else {
      // odd waves: js 7 -> 0 (phase-staggered vs even waves)
#pragma unroll
      for (int nc = 0; nc < 2; ++nc) {
        int col = nc * 16 + l15;
        int byte = col * 512 + ((7 * 64 + lg * 16) ^ ((col & 7) << 4));
        bfr[1][nc] = *(const short8*)(rb + byte);
      }
      JS_ITER(7, 6, 1) JS_ITER(6, 5, 1) JS_ITER(5, 4, 1) JS_ITER(4, 3, 1)
      JS_ITER(3, 2, 1) JS_ITER(2, 1, 1) JS_ITER(1, 0, 1) JS_ITER(0, 7, 0)
    }

    // write next stage (waitcnt lands here, after compute)
    if (t < 63) {
      uint4 pk;
      pk.x = cvtpk(wa.x, wa.y); pk.y = cvtpk(wa.z, wa.w);
      pk.z = cvtpk(wb.x, wb.y); pk.w = cvtpk(wb.z, wb.w);
      *(uint4*)((char*)smemv + nxt * 16384 + wbyte) = pk;
    }
    __syncthreads();
    cur = nxt;
  }

  // epilogue: split-K accumulate (16 adds per output elem over whole grid)
#pragma unroll
  for (int g = 0; g < 4; ++g)
#pragma unroll
    for (int nc = 0; nc < 2; ++nc)
#pragma unroll
      for (int r = 0; r < 4; ++r) {
        int b = wrow + g * 16 + lg * 4 + r;
        int n = ntile * 32 + nc * 16 + l15;
        unsafeAtomicAdd(&accg[(size_t)b * 1024 + n], acc[g][nc][r]);
      }
}

// ---------------- merge = h @ Wmerge (1024x512x1024 bf16 MFMA) -------------
__device__ __forceinline__ short8 ld8bf(const ushort_t* p) {
  union { uint4 v; short8 s; } cv;
  cv.v = *(const uint4*)p;
  return cv.s;
}

__global__ __launch_bounds__(256) void merge_k(const ushort_t* __restrict__ hb,
                                               const ushort_t* __restrict__ WmT,
                                               float* __restrict__ mout) {
  const int tid = threadIdx.x;
  const int wave = tid >> 6, lane = tid & 63;
  const int l15 = lane & 15, lg = lane >> 4;
  const int m0 = blockIdx.x * 64 + (wave >> 1) * 32;
  const int n0 = blockIdx.y * 64 + (wave & 1) * 32;
  const f32x4 z4 = {0.f, 0.f, 0.f, 0.f};
  f32x4 acc[2][2];
#pragma unroll
  for (int g = 0; g < 2; ++g)
#pragma unroll
    for (int nc = 0; nc < 2; ++nc) acc[g][nc] = z4;

  for (int k = 0; k < 1024; k += 32) {
    short8 af[2], bf[2];
#pragma unroll
    for (int g = 0; g < 2; ++g)
      af[g] = ld8bf(hb + (size_t)(m0 + g * 16 + l15) * 1024 + k + lg * 8);
#pragma unroll
    for (int nc = 0; nc < 2; ++nc)
      bf[nc] = ld8bf(WmT + (size_t)(n0 + nc * 16 + l15) * 1024 + k + lg * 8);
#pragma unroll
    for (int g = 0; g < 2; ++g)
#pragma unroll
      for (int nc = 0; nc < 2; ++nc)
        acc[g][nc] = __builtin_amdgcn_mfma_f32_16x16x32_bf16(
            af[g], bf[nc], acc[g][nc], 0, 0, 0);
  }
#pragma unroll
  for (int g = 0; g < 2; ++g)
#pragma unroll
    for (int nc = 0; nc < 2; ++nc)
#pragma unroll
      for (int r = 0; r < 4; ++r)
        mout[(size_t)(m0 + g * 16 + lg * 4 + r) * 512 + n0 + nc * 16 + l15] =
            acc[g][nc][r];
}

// ---------------- finalize -------------------------------------------------
__global__ void fin_k(const float* __restrict__ accg, const float* __restrict__ mout,
                      const float* __restrict__ b1, const float* __restrict__ b2,
                      float* __restrict__ out) {
  int idx = blockIdx.x * 256 + threadIdx.x;  // 524288 total
  int b = idx >> 9, l = idx & 511;
  float m1 = accg[(size_t)b * 1024 + l];
  float m2 = accg[(size_t)b * 1024 + 512 + l];
  float st = tanhf(m1 + b1[l]);
  float u = 1.f / (1.f + expf(-(m2 + b2[l])));
  out[idx] = u * st + (1.f - u) * mout[idx];
}

extern "C" void kernel_launch(void* const* d_in, const int* in_sizes, int n_in,
                              void* d_out, int out_size, void* d_ws, size_t ws_size,
                              hipStream_t stream) {
  const float* in0 = (const float*)d_in[0];
  const float* in1 = (const float*)d_in[1];
  const float* s0  = (const float*)d_in[2];
  const float* s1  = (const float*)d_in[3];
  const float* W1  = (const float*)d_in[4];
  const float* b1  = (const float*)d_in[5];
  const float* W2  = (const float*)d_in[6];
  const float* b2  = (const float*)d_in[7];
  const float* Wm  = (const float*)d_in[8];
  float* out = (float*)d_out;

  char* ws = (char*)d_ws;
  float*    accg = (float*)(ws + 0);                          // 4 MB
  float*    mout = (float*)(ws + (4u << 20));                 // 2 MB
  ushort_t* hb   = (ushort_t*)(ws + (6u << 20));              // 2 MB
  ushort_t* xb   = (ushort_t*)(ws + (8u << 20));              // 512 KB
  ushort_t* WmT  = (ushort_t*)(ws + (8u << 20) + (512u << 10)); // 1 MB

  hipMemsetAsync(accg, 0, 4u << 20, stream);
  prep_k<<<400, 256, 0, stream>>>(in0, in1, s0, s1, Wm, hb, xb, WmT);
  bilin_k<<<dim3(32, 16), 1024, 0, stream>>>(W1, W2, hb, xb, accg);
  merge_k<<<dim3(16, 8), 256, 0, stream>>>(hb, WmT, mout);
  fin_k<<<2048, 256, 0, stream>>>(accg, mout, b1, b2, out);
}

// Round 15
// 835.266 us; speedup vs baseline: 2.9177x; 2.9177x over previous
//
#include <hip/hip_runtime.h>
#include <hip/hip_bf16.h>

// TensorizedRNN: m1/m2 = einsum('bj,bk,ljk->bl', h, x, W{1,2}) as bf16-MFMA GEMM
// with virtual A = h (outer) x, K = 1024*256 = 262144.
// B=1024, I2=256, H=512, N=1024 (W1||W2), J=1024.
//
// R15: same R9 inner loop + work decomposition, but 512-THREAD blocks.
// Evidence: R1/R2 (512-thr) were granted 128 arch VGPRs; all 1024-thr rounds
// got 64 -- the grant is thread-count-determined. At 128 arch regs the R9
// body fits with headroom:
//  - 8 waves x 128 rows/wave (acc[8][2] = 64 AGPR), block = 1024 rows x 32
//    cols, grid (32,16) -> W read exactly once.
//  - arch demand ~116 (xc packed 32 + hc 32 + bfr 16 + staging 16 + addr):
//    fits 128 even if waves_per_eu(2,2)'s 256 request is ignored.
//  - LDS padded 84 KB -> 1 block/CU -> 2 waves/SIMD, 16-MFMA bursts,
//    half the waves per barrier vs R9.
// Spill detector: WRITE_SIZE ~72-90 MB; GB-scale or flat dur => resubmit R9.

typedef __attribute__((ext_vector_type(8))) short short8;
typedef __attribute__((ext_vector_type(4))) float f32x4;
typedef __attribute__((ext_vector_type(2))) float f32x2;
typedef unsigned short ushort_t;

// f32 pair -> packed bf16 (low16 = a, high16 = b), single HW instr
__device__ __forceinline__ unsigned cvtpk(float a, float b) {
  unsigned r;
  asm("v_cvt_pk_bf16_f32 %0, %1, %2" : "=v"(r) : "v"(a), "v"(b));
  return r;
}

// packed f32 multiply, single HW instr
__device__ __forceinline__ f32x2 pkmul(f32x2 a, f32x2 b) {
  f32x2 r;
  asm("v_pk_mul_f32 %0, %1, %2" : "=v"(r) : "v"(a), "v"(b));
  return r;
}

__device__ __forceinline__ ushort_t f2bu(float f) {
  __hip_bfloat16 b = __float2bfloat16(f);
  union { __hip_bfloat16 b; ushort_t u; } cv;
  cv.b = b;
  return cv.u;
}

// ---------------- prep: hb16[b][j], xb16[b][kx], WmergeT[l][j] (all bf16) ---
__global__ void prep_k(const float* __restrict__ in0, const float* __restrict__ in1,
                       const float* __restrict__ s0, const float* __restrict__ s1,
                       const float* __restrict__ Wm,
                       ushort_t* __restrict__ hb, ushort_t* __restrict__ xb,
                       ushort_t* __restrict__ WmT) {
  __shared__ float tl[64][65];
  const int bid = blockIdx.x, t = threadIdx.x;
  if (bid < 256) {  // hb16: 1M elems, 4096/block
#pragma unroll
    for (int i = 0; i < 4; ++i) {
      int e = bid * 4096 + i * 1024 + t * 4;
      int b = e >> 10, j = e & 1023;
      const float* src = (j < 512) ? (s0 + (size_t)b * 512 + j)
                                   : (s1 + (size_t)b * 512 + j - 512);
      float4 v = *(const float4*)src;
      ushort4 o;
      o.x = f2bu(v.x); o.y = f2bu(v.y); o.z = f2bu(v.z); o.w = f2bu(v.w);
      *(ushort4*)(hb + e) = o;
    }
  } else if (bid < 272) {  // xb16: 256K elems, 16384/block
#pragma unroll
    for (int i = 0; i < 16; ++i) {
      int e = (bid - 256) * 16384 + i * 1024 + t * 4;
      int b = e >> 8, kx = e & 255;
      const float* src = (kx < 128) ? (in0 + (size_t)b * 128 + kx)
                                    : (in1 + (size_t)b * 128 + kx - 128);
      float4 v = *(const float4*)src;
      ushort4 o;
      o.x = f2bu(v.x); o.y = f2bu(v.y); o.z = f2bu(v.z); o.w = f2bu(v.w);
      *(ushort4*)(xb + e) = o;
    }
  } else {  // Wmerge [1024][512] -> WmT [512][1024], 64x64 tiles
    int q = bid - 272;           // 0..127
    int j0 = (q >> 3) * 64;
    int l0 = (q & 7) * 64;
#pragma unroll
    for (int i = 0; i < 16; ++i) {
      int idx = i * 256 + t; int r = idx >> 6, c = idx & 63;
      tl[r][c] = Wm[(size_t)(j0 + r) * 512 + l0 + c];
    }
    __syncthreads();
#pragma unroll
    for (int i = 0; i < 16; ++i) {
      int idx = i * 256 + t; int r = idx >> 6, c = idx & 63;
      WmT[(size_t)(l0 + r) * 1024 + j0 + c] = f2bu(tl[c][r]);
    }
  }
}

// ---------------- main bilinear GEMM --------------------------------------
// grid (32 ntiles, 16 kchunks) = 512 blocks, 512 threads (8 waves).
// Block: all 1024 batch rows x 32 n-cols; K-chunk = 512 j's x 32 kx's,
// consumed in 64 stages of 8 j. Wave tile 128 rows x 32 cols.
// Per stage: issue W(t+1) loads (16 f32/thread) -> compute 8 js
// (bfr reg-dbuf, 16 MFMA bursts) -> cvt+ds_write -> barrier.
__global__ __launch_bounds__(512)
__attribute__((amdgpu_waves_per_eu(2, 2))) void bilin_k(
    const float* __restrict__ W1, const float* __restrict__ W2,
    const ushort_t* __restrict__ hb, const ushort_t* __restrict__ xb,
    float* __restrict__ accg) {
  // 2 x 16 KB bf16 tile + pad to 84 KB so only ONE block fits per CU.
  __shared__ uint4 smemv[5376];  // 86016 B

  const int ntile = blockIdx.x;         // 0..31 -> n cols ntile*32..+31
  const int chunk = blockIdx.y;         // 0..15
  const int kxwin = (chunk & 7) * 32;   // kx window
  const int jbase0 = (chunk >> 3) * 512;
  const int tid = threadIdx.x;
  const int wave = tid >> 6;            // 0..7
  const int lane = tid & 63;
  const int l15 = lane & 15;
  const int lg = lane >> 4;
  const int wrow = wave * 128;          // wave's 128 batch rows

  // W-staging role: col 0..31 (tid>>4), within-col c 0..15:
  //   j_sub = c>>1, half = c&1 -> 16 consecutive f32.
  const int scol = tid >> 4;
  const int cc = tid & 15;
  const int sjs = cc >> 1;
  const int shalf = cc & 1;
  const int swzw = (scol & 7) << 4;
  const int wb0 = scol * 512 + ((sjs * 64 + shalf * 32) ^ swzw);
  const int wb1 = scol * 512 + ((sjs * 64 + shalf * 32 + 16) ^ swzw);

  const float* Wsel = (ntile < 16) ? W1 : W2;
  const float* gW = Wsel + (size_t)((ntile & 15) * 32 + scol) * 262144 +
                    (size_t)(jbase0 + sjs) * 256 + kxwin + shalf * 16;
  // stage stride = 8 j * 256 = 2048 floats.

  // per-lane x cache, PACKED bf16 (t-invariant): 32 regs
  uint4 xc[8];
#pragma unroll
  for (int g = 0; g < 8; ++g)
    xc[g] = *(const uint4*)(xb + (size_t)(wrow + g * 16 + l15) * 256 + kxwin + lg * 8);

  f32x4 acc[8][2];
  const f32x4 z4 = {0.f, 0.f, 0.f, 0.f};
#pragma unroll
  for (int g = 0; g < 8; ++g)
#pragma unroll
    for (int nc = 0; nc < 2; ++nc) acc[g][nc] = z4;

  // prologue: stage t=0 into buf[0]
  {
    float4 v0 = *(const float4*)gW;
    float4 v1 = *(const float4*)(gW + 4);
    float4 v2 = *(const float4*)(gW + 8);
    float4 v3 = *(const float4*)(gW + 12);
    uint4 p0, p1;
    p0.x = cvtpk(v0.x, v0.y); p0.y = cvtpk(v0.z, v0.w);
    p0.z = cvtpk(v1.x, v1.y); p0.w = cvtpk(v1.z, v1.w);
    p1.x = cvtpk(v2.x, v2.y); p1.y = cvtpk(v2.z, v2.w);
    p1.z = cvtpk(v3.x, v3.y); p1.w = cvtpk(v3.z, v3.w);
    *(uint4*)((char*)smemv + wb0) = p0;
    *(uint4*)((char*)smemv + wb1) = p1;
  }
  __syncthreads();

  int cur = 0;
  for (int t = 0; t < 64; ++t) {
    const int nxt = cur ^ 1;
    // issue next-stage W loads early (drained after compute)
    float4 v0, v1, v2, v3;
    if (t < 63) {
      const float* gp = gW + (size_t)(t + 1) * 2048;
      v0 = *(const float4*)gp;
      v1 = *(const float4*)(gp + 4);
      v2 = *(const float4*)(gp + 8);
      v3 = *(const float4*)(gp + 12);
    }

    // h for this stage: 8 j's per row (16 B), 8 row-groups = 32 regs
    const int jw = jbase0 + t * 8;
    uint4 hc[8];
#pragma unroll
    for (int g = 0; g < 8; ++g)
      hc[g] = *(const uint4*)(hb + (size_t)(wrow + g * 16 + l15) * 1024 + jw);

    const char* rb = (const char*)smemv + cur * 16384;

    // register double-buffer for B fragments: preload js=0
    short8 bfr[2][2];
#pragma unroll
    for (int nc = 0; nc < 2; ++nc) {
      int col = nc * 16 + l15;
      int byte = col * 512 + ((lg * 16) ^ ((col & 7) << 4));
      bfr[0][nc] = *(const short8*)(rb + byte);
    }

#pragma unroll
    for (int js = 0; js < 8; ++js) {
      const int pb = js & 1, nb = pb ^ 1;
      if (js < 7) {
#pragma unroll
        for (int nc = 0; nc < 2; ++nc) {
          int col = nc * 16 + l15;
          int byte = col * 512 + (((js + 1) * 64 + lg * 16) ^ ((col & 7) << 4));
          bfr[nb][nc] = *(const short8*)(rb + byte);
        }
      }
      __builtin_amdgcn_s_setprio(1);
#pragma unroll
      for (int g = 0; g < 8; ++g) {
        unsigned hwrd = (js < 2) ? hc[g].x : (js < 4) ? hc[g].y
                       : (js < 6) ? hc[g].z : hc[g].w;
        float hf = __uint_as_float((js & 1) ? (hwrd & 0xFFFF0000u) : (hwrd << 16));
        f32x2 hf2; hf2[0] = hf; hf2[1] = hf;
        unsigned xw[4] = {xc[g].x, xc[g].y, xc[g].z, xc[g].w};
        union { unsigned u[4]; short8 s; } av;
#pragma unroll
        for (int p = 0; p < 4; ++p) {
          f32x2 xv;
          xv[0] = __uint_as_float(xw[p] << 16);
          xv[1] = __uint_as_float(xw[p] & 0xFFFF0000u);
          f32x2 m = pkmul(xv, hf2);
          av.u[p] = cvtpk(m[0], m[1]);
        }
        short8 afr = av.s;
#pragma unroll
        for (int nc = 0; nc < 2; ++nc)
          acc[g][nc] = __builtin_amdgcn_mfma_f32_16x16x32_bf16(
              afr, bfr[pb][nc], acc[g][nc], 0, 0, 0);
      }
      __builtin_amdgcn_s_setprio(0);
    }

    // write next stage (vmcnt wait lands here, after compute)
    if (t < 63) {
      uint4 p0, p1;
      p0.x = cvtpk(v0.x, v0.y); p0.y = cvtpk(v0.z, v0.w);
      p0.z = cvtpk(v1.x, v1.y); p0.w = cvtpk(v1.z, v1.w);
      p1.x = cvtpk(v2.x, v2.y); p1.y = cvtpk(v2.z, v2.w);
      p1.z = cvtpk(v3.x, v3.y); p1.w = cvtpk(v3.z, v3.w);
      *(uint4*)((char*)smemv + nxt * 16384 + wb0) = p0;
      *(uint4*)((char*)smemv + nxt * 16384 + wb1) = p1;
    }
    __syncthreads();
    cur = nxt;
  }

  // epilogue: split-K accumulate (16 adds per output elem over whole grid)
#pragma unroll
  for (int g = 0; g < 8; ++g)
#pragma unroll
    for (int nc = 0; nc < 2; ++nc)
#pragma unroll
      for (int r = 0; r < 4; ++r) {
        int b = wrow + g * 16 + lg * 4 + r;
        int n = ntile * 32 + nc * 16 + l15;
        unsafeAtomicAdd(&accg[(size_t)b * 1024 + n], acc[g][nc][r]);
      }
}

// ---------------- merge = h @ Wmerge (1024x512x1024 bf16 MFMA) -------------
__device__ __forceinline__ short8 ld8bf(const ushort_t* p) {
  union { uint4 v; short8 s; } cv;
  cv.v = *(const uint4*)p;
  return cv.s;
}

__global__ __launch_bounds__(256) void merge_k(const ushort_t* __restrict__ hb,
                                               const ushort_t* __restrict__ WmT,
                                               float* __restrict__ mout) {
  const int tid = threadIdx.x;
  const int wave = tid >> 6, lane = tid & 63;
  const int l15 = lane & 15, lg = lane >> 4;
  const int m0 = blockIdx.x * 64 + (wave >> 1) * 32;
  const int n0 = blockIdx.y * 64 + (wave & 1) * 32;
  const f32x4 z4 = {0.f, 0.f, 0.f, 0.f};
  f32x4 acc[2][2];
#pragma unroll
  for (int g = 0; g < 2; ++g)
#pragma unroll
    for (int nc = 0; nc < 2; ++nc) acc[g][nc] = z4;

  for (int k = 0; k < 1024; k += 32) {
    short8 af[2], bf[2];
#pragma unroll
    for (int g = 0; g < 2; ++g)
      af[g] = ld8bf(hb + (size_t)(m0 + g * 16 + l15) * 1024 + k + lg * 8);
#pragma unroll
    for (int nc = 0; nc < 2; ++nc)
      bf[nc] = ld8bf(WmT + (size_t)(n0 + nc * 16 + l15) * 1024 + k + lg * 8);
#pragma unroll
    for (int g = 0; g < 2; ++g)
#pragma unroll
      for (int nc = 0; nc < 2; ++nc)
        acc[g][nc] = __builtin_amdgcn_mfma_f32_16x16x32_bf16(
            af[g], bf[nc], acc[g][nc], 0, 0, 0);
  }
#pragma unroll
  for (int g = 0; g < 2; ++g)
#pragma unroll
    for (int nc = 0; nc < 2; ++nc)
#pragma unroll
      for (int r = 0; r < 4; ++r)
        mout[(size_t)(m0 + g * 16 + lg * 4 + r) * 512 + n0 + nc * 16 + l15] =
            acc[g][nc][r];
}

// ---------------- finalize -------------------------------------------------
__global__ void fin_k(const float* __restrict__ accg, const float* __restrict__ mout,
                      const float* __restrict__ b1, const float* __restrict__ b2,
                      float* __restrict__ out) {
  int idx = blockIdx.x * 256 + threadIdx.x;  // 524288 total
  int b = idx >> 9, l = idx & 511;
  float m1 = accg[(size_t)b * 1024 + l];
  float m2 = accg[(size_t)b * 1024 + 512 + l];
  float st = tanhf(m1 + b1[l]);
  float u = 1.f / (1.f + expf(-(m2 + b2[l])));
  out[idx] = u * st + (1.f - u) * mout[idx];
}

extern "C" void kernel_launch(void* const* d_in, const int* in_sizes, int n_in,
                              void* d_out, int out_size, void* d_ws, size_t ws_size,
                              hipStream_t stream) {
  const float* in0 = (const float*)d_in[0];
  const float* in1 = (const float*)d_in[1];
  const float* s0  = (const float*)d_in[2];
  const float* s1  = (const float*)d_in[3];
  const float* W1  = (const float*)d_in[4];
  const float* b1  = (const float*)d_in[5];
  const float* W2  = (const float*)d_in[6];
  const float* b2  = (const float*)d_in[7];
  const float* Wm  = (const float*)d_in[8];
  float* out = (float*)d_out;

  char* ws = (char*)d_ws;
  float*    accg = (float*)(ws + 0);                          // 4 MB
  float*    mout = (float*)(ws + (4u << 20));                 // 2 MB
  ushort_t* hb   = (ushort_t*)(ws + (6u << 20));              // 2 MB
  ushort_t* xb   = (ushort_t*)(ws + (8u << 20));              // 512 KB
  ushort_t* WmT  = (ushort_t*)(ws + (8u << 20) + (512u << 10)); // 1 MB

  hipMemsetAsync(accg, 0, 4u << 20, stream);
  prep_k<<<400, 256, 0, stream>>>(in0, in1, s0, s1, Wm, hb, xb, WmT);
  bilin_k<<<dim3(32, 16), 512, 0, stream>>>(W1, W2, hb, xb, accg);
  merge_k<<<dim3(16, 8), 256, 0, stream>>>(hb, WmT, mout);
  fin_k<<<2048, 256, 0, stream>>>(accg, mout, b1, b2, out);
}

// Round 16
// 833.357 us; speedup vs baseline: 2.9244x; 1.0023x over previous
//
#include <hip/hip_runtime.h>
#include <hip/hip_bf16.h>

// TensorizedRNN: m1/m2 = einsum('bj,bk,ljk->bl', h, x, W{1,2}) as bf16-MFMA GEMM
// with virtual A = h (outer) x, K = 1024*256 = 262144.
// B=1024, I2=256, H=512, N=1024 (W1||W2), J=1024.
//
// R16 = R15 with 2 CO-RESIDENT blocks/CU (the R13 idea, done right).
// R15 evidence: 512-thr grant = 112 regs, zero spill, but 2 waves/SIMD
// (Occ 23%) -> no TLP, wall = serial pipe sum, flat vs R9.
// HW pool check: 4 waves x 112 regs = 448 <= 512/SIMD -> two 512-thr blocks
// CAN co-reside per CU. R13 failed on (4,4)'s 64-reg grant (spill) + z-split
// double-fetch; both fixed here:
//  - attr (2,4): budget from min=2 keeps the 112-reg grant; max=4 lets HW
//    run 4 waves/SIMD.
//  - LDS 64 KB (2x16 KB buffers + pad): 160/64 -> exactly 2 blocks/CU.
//  - no z-split: 512 blocks / 256 CUs already = 2 resident blocks.
// Independent barriers -> per-SIMD phase diversity (one block MFMAs while
// the other stages/A-gens). Spill detector: WRITE_SIZE ~65 MB.

typedef __attribute__((ext_vector_type(8))) short short8;
typedef __attribute__((ext_vector_type(4))) float f32x4;
typedef __attribute__((ext_vector_type(2))) float f32x2;
typedef unsigned short ushort_t;

// f32 pair -> packed bf16 (low16 = a, high16 = b), single HW instr
__device__ __forceinline__ unsigned cvtpk(float a, float b) {
  unsigned r;
  asm("v_cvt_pk_bf16_f32 %0, %1, %2" : "=v"(r) : "v"(a), "v"(b));
  return r;
}

// packed f32 multiply, single HW instr
__device__ __forceinline__ f32x2 pkmul(f32x2 a, f32x2 b) {
  f32x2 r;
  asm("v_pk_mul_f32 %0, %1, %2" : "=v"(r) : "v"(a), "v"(b));
  return r;
}

__device__ __forceinline__ ushort_t f2bu(float f) {
  __hip_bfloat16 b = __float2bfloat16(f);
  union { __hip_bfloat16 b; ushort_t u; } cv;
  cv.b = b;
  return cv.u;
}

// ---------------- prep: hb16[b][j], xb16[b][kx], WmergeT[l][j] (all bf16) ---
__global__ void prep_k(const float* __restrict__ in0, const float* __restrict__ in1,
                       const float* __restrict__ s0, const float* __restrict__ s1,
                       const float* __restrict__ Wm,
                       ushort_t* __restrict__ hb, ushort_t* __restrict__ xb,
                       ushort_t* __restrict__ WmT) {
  __shared__ float tl[64][65];
  const int bid = blockIdx.x, t = threadIdx.x;
  if (bid < 256) {  // hb16: 1M elems, 4096/block
#pragma unroll
    for (int i = 0; i < 4; ++i) {
      int e = bid * 4096 + i * 1024 + t * 4;
      int b = e >> 10, j = e & 1023;
      const float* src = (j < 512) ? (s0 + (size_t)b * 512 + j)
                                   : (s1 + (size_t)b * 512 + j - 512);
      float4 v = *(const float4*)src;
      ushort4 o;
      o.x = f2bu(v.x); o.y = f2bu(v.y); o.z = f2bu(v.z); o.w = f2bu(v.w);
      *(ushort4*)(hb + e) = o;
    }
  } else if (bid < 272) {  // xb16: 256K elems, 16384/block
#pragma unroll
    for (int i = 0; i < 16; ++i) {
      int e = (bid - 256) * 16384 + i * 1024 + t * 4;
      int b = e >> 8, kx = e & 255;
      const float* src = (kx < 128) ? (in0 + (size_t)b * 128 + kx)
                                    : (in1 + (size_t)b * 128 + kx - 128);
      float4 v = *(const float4*)src;
      ushort4 o;
      o.x = f2bu(v.x); o.y = f2bu(v.y); o.z = f2bu(v.z); o.w = f2bu(v.w);
      *(ushort4*)(xb + e) = o;
    }
  } else {  // Wmerge [1024][512] -> WmT [512][1024], 64x64 tiles
    int q = bid - 272;           // 0..127
    int j0 = (q >> 3) * 64;
    int l0 = (q & 7) * 64;
#pragma unroll
    for (int i = 0; i < 16; ++i) {
      int idx = i * 256 + t; int r = idx >> 6, c = idx & 63;
      tl[r][c] = Wm[(size_t)(j0 + r) * 512 + l0 + c];
    }
    __syncthreads();
#pragma unroll
    for (int i = 0; i < 16; ++i) {
      int idx = i * 256 + t; int r = idx >> 6, c = idx & 63;
      WmT[(size_t)(l0 + r) * 1024 + j0 + c] = f2bu(tl[c][r]);
    }
  }
}

// ---------------- main bilinear GEMM --------------------------------------
// grid (32 ntiles, 16 kchunks) = 512 blocks, 512 threads (8 waves),
// 2 blocks co-resident per CU. Block: all 1024 batch rows x 32 n-cols;
// K-chunk = 512 j's x 32 kx's, 64 stages of 8 j. Wave tile 128x32.
// Per stage: issue W(t+1) loads (16 f32/thread) -> compute 8 js
// (bfr reg-dbuf, 16 MFMA bursts) -> cvt+ds_write -> barrier.
__global__ __launch_bounds__(512)
__attribute__((amdgpu_waves_per_eu(2, 4))) void bilin_k(
    const float* __restrict__ W1, const float* __restrict__ W2,
    const ushort_t* __restrict__ hb, const ushort_t* __restrict__ xb,
    float* __restrict__ accg) {
  // 2 x 16 KB bf16 buffers + pad to 64 KB: exactly 2 blocks/CU (160/64=2).
  __shared__ uint4 smemv[4096];  // 65536 B; buf i at byte i*16384

  const int ntile = blockIdx.x;         // 0..31 -> n cols ntile*32..+31
  const int chunk = blockIdx.y;         // 0..15
  const int kxwin = (chunk & 7) * 32;   // kx window
  const int jbase0 = (chunk >> 3) * 512;
  const int tid = threadIdx.x;
  const int wave = tid >> 6;            // 0..7
  const int lane = tid & 63;
  const int l15 = lane & 15;
  const int lg = lane >> 4;
  const int wrow = wave * 128;          // wave's 128 batch rows

  // W-staging role: col 0..31 (tid>>4), within-col c 0..15:
  //   j_sub = c>>1, half = c&1 -> 16 consecutive f32.
  const int scol = tid >> 4;
  const int cc = tid & 15;
  const int sjs = cc >> 1;
  const int shalf = cc & 1;
  const int swzw = (scol & 7) << 4;
  const int wb0 = scol * 512 + ((sjs * 64 + shalf * 32) ^ swzw);
  const int wb1 = scol * 512 + ((sjs * 64 + shalf * 32 + 16) ^ swzw);

  const float* Wsel = (ntile < 16) ? W1 : W2;
  const float* gW = Wsel + (size_t)((ntile & 15) * 32 + scol) * 262144 +
                    (size_t)(jbase0 + sjs) * 256 + kxwin + shalf * 16;
  // stage stride = 8 j * 256 = 2048 floats.

  // per-lane x cache, PACKED bf16 (t-invariant): 32 regs
  uint4 xc[8];
#pragma unroll
  for (int g = 0; g < 8; ++g)
    xc[g] = *(const uint4*)(xb + (size_t)(wrow + g * 16 + l15) * 256 + kxwin + lg * 8);

  f32x4 acc[8][2];
  const f32x4 z4 = {0.f, 0.f, 0.f, 0.f};
#pragma unroll
  for (int g = 0; g < 8; ++g)
#pragma unroll
    for (int nc = 0; nc < 2; ++nc) acc[g][nc] = z4;

  // prologue: stage t=0 into buf[0]
  {
    float4 v0 = *(const float4*)gW;
    float4 v1 = *(const float4*)(gW + 4);
    float4 v2 = *(const float4*)(gW + 8);
    float4 v3 = *(const float4*)(gW + 12);
    uint4 p0, p1;
    p0.x = cvtpk(v0.x, v0.y); p0.y = cvtpk(v0.z, v0.w);
    p0.z = cvtpk(v1.x, v1.y); p0.w = cvtpk(v1.z, v1.w);
    p1.x = cvtpk(v2.x, v2.y); p1.y = cvtpk(v2.z, v2.w);
    p1.z = cvtpk(v3.x, v3.y); p1.w = cvtpk(v3.z, v3.w);
    *(uint4*)((char*)smemv + wb0) = p0;
    *(uint4*)((char*)smemv + wb1) = p1;
  }
  __syncthreads();

  int cur = 0;
  for (int t = 0; t < 64; ++t) {
    const int nxt = cur ^ 1;
    // issue next-stage W loads early (drained after compute)
    float4 v0, v1, v2, v3;
    if (t < 63) {
      const float* gp = gW + (size_t)(t + 1) * 2048;
      v0 = *(const float4*)gp;
      v1 = *(const float4*)(gp + 4);
      v2 = *(const float4*)(gp + 8);
      v3 = *(const float4*)(gp + 12);
    }

    // h for this stage: 8 j's per row (16 B), 8 row-groups = 32 regs
    const int jw = jbase0 + t * 8;
    uint4 hc[8];
#pragma unroll
    for (int g = 0; g < 8; ++g)
      hc[g] = *(const uint4*)(hb + (size_t)(wrow + g * 16 + l15) * 1024 + jw);

    const char* rb = (const char*)smemv + cur * 16384;

    // register double-buffer for B fragments: preload js=0
    short8 bfr[2][2];
#pragma unroll
    for (int nc = 0; nc < 2; ++nc) {
      int col = nc * 16 + l15;
      int byte = col * 512 + ((lg * 16) ^ ((col & 7) << 4));
      bfr[0][nc] = *(const short8*)(rb + byte);
    }

#pragma unroll
    for (int js = 0; js < 8; ++js) {
      const int pb = js & 1, nb = pb ^ 1;
      if (js < 7) {
#pragma unroll
        for (int nc = 0; nc < 2; ++nc) {
          int col = nc * 16 + l15;
          int byte = col * 512 + (((js + 1) * 64 + lg * 16) ^ ((col & 7) << 4));
          bfr[nb][nc] = *(const short8*)(rb + byte);
        }
      }
      __builtin_amdgcn_s_setprio(1);
#pragma unroll
      for (int g = 0; g < 8; ++g) {
        unsigned hwrd = (js < 2) ? hc[g].x : (js < 4) ? hc[g].y
                       : (js < 6) ? hc[g].z : hc[g].w;
        float hf = __uint_as_float((js & 1) ? (hwrd & 0xFFFF0000u) : (hwrd << 16));
        f32x2 hf2; hf2[0] = hf; hf2[1] = hf;
        unsigned xw[4] = {xc[g].x, xc[g].y, xc[g].z, xc[g].w};
        union { unsigned u[4]; short8 s; } av;
#pragma unroll
        for (int p = 0; p < 4; ++p) {
          f32x2 xv;
          xv[0] = __uint_as_float(xw[p] << 16);
          xv[1] = __uint_as_float(xw[p] & 0xFFFF0000u);
          f32x2 m = pkmul(xv, hf2);
          av.u[p] = cvtpk(m[0], m[1]);
        }
        short8 afr = av.s;
#pragma unroll
        for (int nc = 0; nc < 2; ++nc)
          acc[g][nc] = __builtin_amdgcn_mfma_f32_16x16x32_bf16(
              afr, bfr[pb][nc], acc[g][nc], 0, 0, 0);
      }
      __builtin_amdgcn_s_setprio(0);
    }

    // write next stage (vmcnt wait lands here, after compute)
    if (t < 63) {
      uint4 p0, p1;
      p0.x = cvtpk(v0.x, v0.y); p0.y = cvtpk(v0.z, v0.w);
      p0.z = cvtpk(v1.x, v1.y); p0.w = cvtpk(v1.z, v1.w);
      p1.x = cvtpk(v2.x, v2.y); p1.y = cvtpk(v2.z, v2.w);
      p1.z = cvtpk(v3.x, v3.y); p1.w = cvtpk(v3.z, v3.w);
      *(uint4*)((char*)smemv + nxt * 16384 + wb0) = p0;
      *(uint4*)((char*)smemv + nxt * 16384 + wb1) = p1;
    }
    __syncthreads();
    cur = nxt;
  }

  // epilogue: split-K accumulate (16 adds per output elem over whole grid)
#pragma unroll
  for (int g = 0; g < 8; ++g)
#pragma unroll
    for (int nc = 0; nc < 2; ++nc)
#pragma unroll
      for (int r = 0; r < 4; ++r) {
        int b = wrow + g * 16 + lg * 4 + r;
        int n = ntile * 32 + nc * 16 + l15;
        unsafeAtomicAdd(&accg[(size_t)b * 1024 + n], acc[g][nc][r]);
      }
}

// ---------------- merge = h @ Wmerge (1024x512x1024 bf16 MFMA) -------------
__device__ __forceinline__ short8 ld8bf(const ushort_t* p) {
  union { uint4 v; short8 s; } cv;
  cv.v = *(const uint4*)p;
  return cv.s;
}

__global__ __launch_bounds__(256) void merge_k(const ushort_t* __restrict__ hb,
                                               const ushort_t* __restrict__ WmT,
                                               float* __restrict__ mout) {
  const int tid = threadIdx.x;
  const int wave = tid >> 6, lane = tid & 63;
  const int l15 = lane & 15, lg = lane >> 4;
  const int m0 = blockIdx.x * 64 + (wave >> 1) * 32;
  const int n0 = blockIdx.y * 64 + (wave & 1) * 32;
  const f32x4 z4 = {0.f, 0.f, 0.f, 0.f};
  f32x4 acc[2][2];
#pragma unroll
  for (int g = 0; g < 2; ++g)
#pragma unroll
    for (int nc = 0; nc < 2; ++nc) acc[g][nc] = z4;

  for (int k = 0; k < 1024; k += 32) {
    short8 af[2], bf[2];
#pragma unroll
    for (int g = 0; g < 2; ++g)
      af[g] = ld8bf(hb + (size_t)(m0 + g * 16 + l15) * 1024 + k + lg * 8);
#pragma unroll
    for (int nc = 0; nc < 2; ++nc)
      bf[nc] = ld8bf(WmT + (size_t)(n0 + nc * 16 + l15) * 1024 + k + lg * 8);
#pragma unroll
    for (int g = 0; g < 2; ++g)
#pragma unroll
      for (int nc = 0; nc < 2; ++nc)
        acc[g][nc] = __builtin_amdgcn_mfma_f32_16x16x32_bf16(
            af[g], bf[nc], acc[g][nc], 0, 0, 0);
  }
#pragma unroll
  for (int g = 0; g < 2; ++g)
#pragma unroll
    for (int nc = 0; nc < 2; ++nc)
#pragma unroll
      for (int r = 0; r < 4; ++r)
        mout[(size_t)(m0 + g * 16 + lg * 4 + r) * 512 + n0 + nc * 16 + l15] =
            acc[g][nc][r];
}

// ---------------- finalize -------------------------------------------------
__global__ void fin_k(const float* __restrict__ accg, const float* __restrict__ mout,
                      const float* __restrict__ b1, const float* __restrict__ b2,
                      float* __restrict__ out) {
  int idx = blockIdx.x * 256 + threadIdx.x;  // 524288 total
  int b = idx >> 9, l = idx & 511;
  float m1 = accg[(size_t)b * 1024 + l];
  float m2 = accg[(size_t)b * 1024 + 512 + l];
  float st = tanhf(m1 + b1[l]);
  float u = 1.f / (1.f + expf(-(m2 + b2[l])));
  out[idx] = u * st + (1.f - u) * mout[idx];
}

extern "C" void kernel_launch(void* const* d_in, const int* in_sizes, int n_in,
                              void* d_out, int out_size, void* d_ws, size_t ws_size,
                              hipStream_t stream) {
  const float* in0 = (const float*)d_in[0];
  const float* in1 = (const float*)d_in[1];
  const float* s0  = (const float*)d_in[2];
  const float* s1  = (const float*)d_in[3];
  const float* W1  = (const float*)d_in[4];
  const float* b1  = (const float*)d_in[5];
  const float* W2  = (const float*)d_in[6];
  const float* b2  = (const float*)d_in[7];
  const float* Wm  = (const float*)d_in[8];
  float* out = (float*)d_out;

  char* ws = (char*)d_ws;
  float*    accg = (float*)(ws + 0);                          // 4 MB
  float*    mout = (float*)(ws + (4u << 20));                 // 2 MB
  ushort_t* hb   = (ushort_t*)(ws + (6u << 20));              // 2 MB
  ushort_t* xb   = (ushort_t*)(ws + (8u << 20));              // 512 KB
  ushort_t* WmT  = (ushort_t*)(ws + (8u << 20) + (512u << 10)); // 1 MB

  hipMemsetAsync(accg, 0, 4u << 20, stream);
  prep_k<<<400, 256, 0, stream>>>(in0, in1, s0, s1, Wm, hb, xb, WmT);
  bilin_k<<<dim3(32, 16), 512, 0, stream>>>(W1, W2, hb, xb, accg);
  merge_k<<<dim3(16, 8), 256, 0, stream>>>(hb, WmT, mout);
  fin_k<<<2048, 256, 0, stream>>>(accg, mout, b1, b2, out);
}